// Round 11
// baseline (604.512 us; speedup 1.0000x reference)
//
#include <hip/hip_runtime.h>

typedef unsigned short u16;
typedef __bf16 bf16x8 __attribute__((ext_vector_type(8)));
typedef __bf16 bf16x2 __attribute__((ext_vector_type(2)));
typedef float f32x4 __attribute__((ext_vector_type(4)));
typedef unsigned short u16x8 __attribute__((ext_vector_type(8)));

#define NNODES 50000
#define NEDGES 640000
#define NGRAPH 256
#define HCHUNK 4096
#define HSPLIT 64
#define NCHUNK 13  // ceil(50000/4096)

__device__ __forceinline__ float bf2f(u16 u) {
  unsigned int v = ((unsigned int)u) << 16; float f; __builtin_memcpy(&f, &v, 4); return f;
}
__device__ __forceinline__ u16 f2bf(float f) {
  unsigned int x; __builtin_memcpy(&x, &f, 4);
  unsigned int lsb = (x >> 16) & 1u;
  x += 0x7fffu + lsb;
  return (u16)(x >> 16);
}
// packed bf16 pair via native casts (compiles to v_cvt_pk_bf16_f32, RNE)
__device__ __forceinline__ unsigned int pkbf(float a, float b) {
  bf16x2 p; p[0] = (__bf16)a; p[1] = (__bf16)b;
  unsigned int r; __builtin_memcpy(&r, &p, 4); return r;
}

// ---------------- safe fallback: zero fp32 output ---------------------------
__global__ void write_zero_f32(float* __restrict__ out, int n) {
  int i = blockIdx.x * 256 + threadIdx.x;
  if (i < n) out[i] = 0.f;
}

// ---------------- weight prep: fp32 -> bf16 transpose (B-layout Wt[n][k]) ---
__global__ void prep_weights(const float* __restrict__ node_w, const float* __restrict__ edge_w1,
                             const float* __restrict__ edge_w2, const float* __restrict__ conv_w1,
                             const float* __restrict__ conv_w2, const float* __restrict__ gate_w1,
                             u16* __restrict__ node_wt, u16* __restrict__ edge_w1t,
                             u16* __restrict__ edge_w2t, u16* __restrict__ conv_w1t,
                             u16* __restrict__ conv_w2t, u16* __restrict__ gate_w1t) {
  int o = blockIdx.x * 256 + threadIdx.x;
  if (o < 8192) { int n = o >> 6, k = o & 63; node_wt[o] = f2bf(node_w[k * 128 + n]); return; }
  o -= 8192;
  if (o < 4096) { int n = o >> 5, k = o & 31;
                  edge_w1t[o] = (k < 16) ? f2bf(edge_w1[k * 128 + n]) : (u16)0; return; }
  o -= 4096;
  if (o < 16384) { int n = o >> 7, k = o & 127; edge_w2t[o] = f2bf(edge_w2[k * 128 + n]); return; }
  o -= 16384;
  if (o < 65536) { int l = o >> 14, r = o & 16383, n = r >> 7, k = r & 127;
                   conv_w1t[o] = f2bf(conv_w1[l * 16384 + k * 128 + n]); return; }
  o -= 65536;
  if (o < 65536) { int l = o >> 14, r = o & 16383, n = r >> 7, k = r & 127;
                   conv_w2t[o] = f2bf(conv_w2[l * 16384 + k * 128 + n]); return; }
  o -= 65536;
  if (o < 8192) { int n = o >> 7, k = o & 127; gate_w1t[o] = f2bf(gate_w1[k * 64 + n]); }
}

// ---------------- CSR build v4: atomic-free, wide scans ---------------------
__global__ __launch_bounds__(256) void hist_k(const int* __restrict__ dst,
                                              int* __restrict__ partial) {
  __shared__ int hloc[HCHUNK];
  int b = blockIdx.x, t = threadIdx.x;
  int c = b >> 6, sp = b & 63;
  for (int j = t; j < HCHUNK; j += 256) hloc[j] = 0;
  __syncthreads();
  int base = c * HCHUNK;
  int e0 = sp * (NEDGES / HSPLIT), e1 = e0 + NEDGES / HSPLIT;
  for (int i = e0 + t; i < e1; i += 256) {
    int d = dst[i] - base;
    if ((unsigned)d < HCHUNK) atomicAdd(&hloc[d], 1);
  }
  __syncthreads();
  for (int j = t; j < HCHUNK; j += 256) {
    int g = base + j;
    if (g < NNODES) partial[(size_t)sp * NNODES + g] = hloc[j];
  }
}
// blocks 0..195: 1 node/thread — merge partials -> counts, in-place
// split-exclusive prefix, per-block (256-node) sums.  block 196: goffs via
// binary search (batch is sorted).
__global__ __launch_bounds__(256) void scan_a(int* __restrict__ partial,
                                              int* __restrict__ counts,
                                              int* __restrict__ bsums,
                                              const int* __restrict__ batch,
                                              int* __restrict__ goffs, int n) {
  __shared__ int sh4[4];
  int b = blockIdx.x, t = threadIdx.x;
  int lane = t & 63, w = t >> 6;
  if (b == 196) {
    int lo = 0, hi = n;  // lower_bound(batch, t)
    while (lo < hi) { int mid = (lo + hi) >> 1; if (batch[mid] < t) lo = mid + 1; else hi = mid; }
    goffs[t] = lo;
    if (t == 0) goffs[256] = n;
    return;
  }
  int g = b * 256 + t;
  int run = 0;
  if (g < n) {
    for (int sp = 0; sp < HSPLIT; sp++) {
      int v = partial[(size_t)sp * NNODES + g];
      partial[(size_t)sp * NNODES + g] = run;
      run += v;
    }
    counts[g] = run;
  }
  int s = run;
  for (int mm = 32; mm; mm >>= 1) s += __shfl_xor(s, mm, 64);
  if (lane == 0) sh4[w] = s;
  __syncthreads();
  if (t == 0) bsums[b] = sh4[0] + sh4[1] + sh4[2] + sh4[3];
}
// offsets: 196 blocks, 1 node/thread; block-parallel prefix of bsums
__global__ __launch_bounds__(256) void scan_c(const int* __restrict__ counts,
                                              const int* __restrict__ bsums,
                                              int* __restrict__ offs, int n) {
  __shared__ int sh4[4];
  __shared__ int wt_[4];
  __shared__ int base_sh;
  int b = blockIdx.x, t = threadIdx.x;
  int lane = t & 63, w = t >> 6;
  // base = sum bsums[0..b)
  int v = (t < b) ? bsums[t] : 0;
  int sv = v;
  for (int mm = 32; mm; mm >>= 1) sv += __shfl_xor(sv, mm, 64);
  if (lane == 0) sh4[w] = sv;
  __syncthreads();
  if (t == 0) base_sh = sh4[0] + sh4[1] + sh4[2] + sh4[3];
  // intra-block exclusive scan of counts
  int g = b * 256 + t;
  int x = (g < n) ? counts[g] : 0;
  int inc = x;
  for (int d = 1; d < 64; d <<= 1) { int y = __shfl_up(inc, (unsigned)d, 64); if (lane >= d) inc += y; }
  if (lane == 63) wt_[w] = inc;
  __syncthreads();
  int add = base_sh;
  for (int i = 0; i < w; i++) add += wt_[i];
  int excl = add + inc - x;
  if (g < n) offs[g] = excl;
  if (b == 0 && t == 0) offs[n] = NEDGES;
}
// deterministic scatter: rank via LDS atomics, slot = offs + split-prefix + rank.
// also emits inv[i] = slot (natural edge id -> CSR position) for edge_encode.
__global__ __launch_bounds__(256) void scatter_k(const int* __restrict__ src,
                                                 const int* __restrict__ dst,
                                                 const int* __restrict__ offs,
                                                 const int* __restrict__ partial,
                                                 int* __restrict__ csr_src,
                                                 int* __restrict__ inv) {
  __shared__ int hloc[HCHUNK];
  int b = blockIdx.x, t = threadIdx.x;
  int c = b >> 6, sp = b & 63;
  for (int j = t; j < HCHUNK; j += 256) hloc[j] = 0;
  __syncthreads();
  int base = c * HCHUNK;
  int e0 = sp * (NEDGES / HSPLIT), e1 = e0 + NEDGES / HSPLIT;
  for (int i = e0 + t; i < e1; i += 256) {
    int d = dst[i];
    int dl = d - base;
    if ((unsigned)dl < HCHUNK) {
      int r = atomicAdd(&hloc[dl], 1);
      int p = offs[d] + partial[(size_t)sp * NNODES + d] + r;
      csr_src[p] = src[i];
      inv[i] = p;
    }
  }
}

// ---------------- MFMA tile helper (A,B both from LDS) ----------------------
template <int KB, int SA, int SB>
__device__ __forceinline__ void mfma_block(const u16* aL, const u16* bL, int m, int quad,
                                           int rbase, f32x4* acc) {
#pragma unroll
  for (int kb = 0; kb < KB; ++kb) {
    bf16x8 a = *(const bf16x8*)(aL + (rbase + m) * SA + kb * 32 + quad * 8);
#pragma unroll
    for (int nt = 0; nt < 8; ++nt) {
      bf16x8 b = *(const bf16x8*)(bL + (nt * 16 + m) * SB + kb * 32 + quad * 8);
      acc[nt] = __builtin_amdgcn_mfma_f32_16x16x32_bf16(a, b, acc[nt], 0, 0, 0);
    }
  }
}

// ---------------- node encoder: hb = bf16(x @ node_w + node_b) --------------
__global__ __launch_bounds__(256) void node_encode(const float* __restrict__ x,
                                                   const u16* __restrict__ wt,
                                                   const float* __restrict__ nb,
                                                   u16* __restrict__ hb, int n) {
  __shared__ alignas(16) u16 sA[64 * 72];
  __shared__ alignas(16) u16 sW[128 * 72];
  int t = threadIdx.x;
  int row0 = blockIdx.x * 64;
#pragma unroll
  for (int i = 0; i < 4; i++) {
    int idx = t + 256 * i; int r = idx >> 4, c = idx & 15;  // 64 rows x 16 float4 (K=64)
    int grow = row0 + r; if (grow > n - 1) grow = n - 1;
    float4 v = *(const float4*)(x + (size_t)grow * 64 + c * 4);
    ushort4 o; o.x = f2bf(v.x); o.y = f2bf(v.y); o.z = f2bf(v.z); o.w = f2bf(v.w);
    *(ushort4*)&sA[r * 72 + c * 4] = o;
  }
#pragma unroll
  for (int i = 0; i < 4; i++) {
    int idx = t + 256 * i; int nr = idx >> 3, c = idx & 7;  // 128 rows x 8 uint4 (K=64)
    *(uint4*)&sW[nr * 72 + c * 8] = *(const uint4*)(wt + nr * 64 + c * 8);
  }
  __syncthreads();
  int lane = t & 63, w = t >> 6, m = lane & 15, quad = lane >> 4, rbase = w * 16;
  f32x4 acc[8];
  f32x4 z4 = {0.f, 0.f, 0.f, 0.f};
#pragma unroll
  for (int i = 0; i < 8; i++) acc[i] = z4;
  mfma_block<2, 72, 72>(sA, sW, m, quad, rbase, acc);
#pragma unroll
  for (int nt = 0; nt < 8; nt++) {
    int col = nt * 16 + m;
    float bb = nb[col];
    f32x4 a4 = acc[nt];
#pragma unroll
    for (int r = 0; r < 4; r++) {
      int grow = row0 + rbase + quad * 4 + r;
      if (grow < n) hb[(size_t)grow * 128 + col] = f2bf(a4[r] + bb);
    }
  }
}

// ---------------- edge encoder v13: natural-order reads, scattered writes ---
// The random side moves from blocking 64B-granule ea gathers (latency-bound,
// stuck at 2.3TB/s across r6-r10) to fire-and-forget 256B-row scatter writes
// via inv[].  ea reads are now fully sequential/coalesced; csr_eid gather
// disappears.
__global__ __launch_bounds__(256) void edge_encode(const float* __restrict__ ea,
                                                   const u16* __restrict__ w1t,
                                                   const u16* __restrict__ w2t,
                                                   const float* __restrict__ b1,
                                                   const float* __restrict__ b2,
                                                   const int* __restrict__ inv,
                                                   u16* __restrict__ e_perm) {
  __shared__ alignas(16) u16 sMid[128 * 132]; // GEMM1 out / GEMM2 in / out tile
  int t = threadIdx.x;
  int lane = t & 63, w = t >> 6, m = lane & 15, quad = lane >> 4;
  int s0 = blockIdx.x * 128;
  int ebase = w * 32;  // this wave's 32 edges (natural order)

  // sequential coalesced global -> reg A-fragments (no barrier before GEMM1)
  bf16x8 af[2];
#pragma unroll
  for (int rt2 = 0; rt2 < 2; rt2++) {
    int eid = s0 + ebase + rt2 * 16 + m;
    bf16x8 a = {};
    if (quad < 2) {
      float4 v0 = *(const float4*)(ea + (size_t)eid * 16 + quad * 8);
      float4 v1 = *(const float4*)(ea + (size_t)eid * 16 + quad * 8 + 4);
      a[0] = (__bf16)v0.x; a[1] = (__bf16)v0.y; a[2] = (__bf16)v0.z; a[3] = (__bf16)v0.w;
      a[4] = (__bf16)v1.x; a[5] = (__bf16)v1.y; a[6] = (__bf16)v1.z; a[7] = (__bf16)v1.w;
    }
    af[rt2] = a;
  }
  bf16x8 w1f[8];
#pragma unroll
  for (int nt = 0; nt < 8; nt++)
    w1f[nt] = *(const bf16x8*)(w1t + (nt * 16 + m) * 32 + quad * 8);

  // GEMM1 (swapped -> D^T), wave-local: 2 row-tiles x 8 ch-tiles
  f32x4 z4 = {0.f, 0.f, 0.f, 0.f};
  f32x4 acc1[16];
#pragma unroll
  for (int i = 0; i < 16; i++) acc1[i] = z4;
#pragma unroll
  for (int rt2 = 0; rt2 < 2; rt2++) {
#pragma unroll
    for (int nt = 0; nt < 8; nt++)
      acc1[rt2 * 8 + nt] = __builtin_amdgcn_mfma_f32_16x16x32_bf16(w1f[nt], af[rt2], acc1[rt2 * 8 + nt], 0, 0, 0);
  }
#pragma unroll
  for (int rt2 = 0; rt2 < 2; rt2++) {
#pragma unroll
    for (int nt = 0; nt < 8; nt++) {
      float4 bb = *(const float4*)&b1[nt * 16 + quad * 4];
      f32x4 a4 = acc1[rt2 * 8 + nt];
      uint2 pk;
      pk.x = pkbf(fmaxf(a4[0] + bb.x, 0.f), fmaxf(a4[1] + bb.y, 0.f));
      pk.y = pkbf(fmaxf(a4[2] + bb.z, 0.f), fmaxf(a4[3] + bb.w, 0.f));
      *(uint2*)&sMid[(ebase + rt2 * 16 + m) * 132 + nt * 16 + quad * 4] = pk;
    }
  }
  bf16x8 w2f[8];
  float4 b2v[2];
#pragma unroll
  for (int ct = 0; ct < 2; ct++) {
    b2v[ct] = *(const float4*)&b2[w * 32 + ct * 16 + quad * 4];
#pragma unroll
    for (int kb = 0; kb < 4; kb++)
      w2f[ct * 4 + kb] = *(const bf16x8*)(w2t + (size_t)(w * 32 + ct * 16 + m) * 128 + kb * 32 + quad * 8);
  }
  __syncthreads();  // b2: sMid complete

  f32x4 acc2[16];
#pragma unroll
  for (int i = 0; i < 16; i++) acc2[i] = z4;
#pragma unroll
  for (int rt = 0; rt < 8; rt++) {
#pragma unroll
    for (int kb = 0; kb < 4; kb++) {
      bf16x8 a = *(const bf16x8*)(&sMid[(rt * 16 + m) * 132 + kb * 32 + quad * 8]);
      acc2[rt * 2 + 0] = __builtin_amdgcn_mfma_f32_16x16x32_bf16(w2f[kb], a, acc2[rt * 2 + 0], 0, 0, 0);
      acc2[rt * 2 + 1] = __builtin_amdgcn_mfma_f32_16x16x32_bf16(w2f[4 + kb], a, acc2[rt * 2 + 1], 0, 0, 0);
    }
  }
  __syncthreads();  // b3: all sMid reads done -> reuse as output tile
#pragma unroll
  for (int rt = 0; rt < 8; rt++) {
#pragma unroll
    for (int ct = 0; ct < 2; ct++) {
      f32x4 a4 = acc2[rt * 2 + ct];
      uint2 pk;
      pk.x = pkbf(a4[0] + b2v[ct].x, a4[1] + b2v[ct].y);
      pk.y = pkbf(a4[2] + b2v[ct].z, a4[3] + b2v[ct].w);
      *(uint2*)&sMid[(rt * 16 + m) * 132 + w * 32 + ct * 16 + quad * 4] = pk;
    }
  }
  __syncthreads();  // b4: out tile ready
  // scattered row copy-out: row r -> CSR slot inv[s0+r]; 256B contiguous/row
#pragma unroll
  for (int i = 0; i < 8; i++) {
    int idx = t + 256 * i; int r = idx >> 4, c = idx & 15;
    int R = inv[s0 + r];
    *(uint4*)(e_perm + (size_t)R * 128 + c * 8) = *(const uint4*)&sMid[r * 132 + c * 8];
  }
}

// ---------------- fused layer v6: per-quarter phase A, 4-edge unroll --------
// GATE=true (last layer): gate MLP runs from sZ in-place.
template <bool GATE>
__global__ __launch_bounds__(256) void layer_k(const u16* __restrict__ hin,
                                               u16* __restrict__ hout,
                                               const u16* __restrict__ e_perm,
                                               const int* __restrict__ offs,
                                               const int* __restrict__ csr_src,
                                               const u16* __restrict__ w1t, const u16* __restrict__ w2t,
                                               const float* __restrict__ b1, const float* __restrict__ b2,
                                               const float* __restrict__ gam, const float* __restrict__ bet,
                                               const u16* __restrict__ gw1t, const float* __restrict__ gb1,
                                               const float* __restrict__ gw2, const float* __restrict__ gb2,
                                               float* __restrict__ gate_out, int n) {
  __shared__ alignas(16) u16 sZ[64 * 132];
  __shared__ alignas(16) u16 sMid[64 * 132];
  int t = threadIdx.x;
  int lane = t & 63, w = t >> 6, m = lane & 15, quad = lane >> 4;
  int row0 = blockIdx.x * 64;
  int li = m;

  // batched offs: one lane-parallel load for the wave's 17 boundaries
  int oidx = row0 + w * 16 + (lane < 16 ? lane : 16);
  if (oidx > n) oidx = n;
  int offv = offs[oidx];

  // ---- phase A: quarter (w,quad) owns nodes w*16+quad*4+{0..3} ----
  for (int k = 0; k < 4; k++) {
    int lr = w * 16 + quad * 4 + k;
    int nd = row0 + lr;
    int ndc = (nd > n - 1) ? (n - 1) : nd;
    int e0 = __shfl(offv, quad * 4 + k, 64), e1 = __shfl(offv, quad * 4 + k + 1, 64);
    u16x8 hv = *(const u16x8*)(hin + (size_t)ndc * 128 + li * 8);
    float a[8];
#pragma unroll
    for (int j = 0; j < 8; j++) a[j] = 0.f;
    int s = e0;
    for (; s + 4 <= e1; s += 4) {  // 4 independent edge streams in flight
      int v0 = csr_src[s], v1 = csr_src[s + 1], v2 = csr_src[s + 2], v3 = csr_src[s + 3];
      u16x8 h0 = *(const u16x8*)(hin + (size_t)v0 * 128 + li * 8);
      u16x8 ee0 = *(const u16x8*)(e_perm + (size_t)s * 128 + li * 8);
      u16x8 h1 = *(const u16x8*)(hin + (size_t)v1 * 128 + li * 8);
      u16x8 ee1 = *(const u16x8*)(e_perm + (size_t)(s + 1) * 128 + li * 8);
      u16x8 h2 = *(const u16x8*)(hin + (size_t)v2 * 128 + li * 8);
      u16x8 ee2 = *(const u16x8*)(e_perm + (size_t)(s + 2) * 128 + li * 8);
      u16x8 h3 = *(const u16x8*)(hin + (size_t)v3 * 128 + li * 8);
      u16x8 ee3 = *(const u16x8*)(e_perm + (size_t)(s + 3) * 128 + li * 8);
#pragma unroll
      for (int j = 0; j < 8; j++) {
        a[j] += fmaxf(bf2f(h0[j]) + bf2f(ee0[j]), 0.f);
        a[j] += fmaxf(bf2f(h1[j]) + bf2f(ee1[j]), 0.f);
        a[j] += fmaxf(bf2f(h2[j]) + bf2f(ee2[j]), 0.f);
        a[j] += fmaxf(bf2f(h3[j]) + bf2f(ee3[j]), 0.f);
      }
    }
    for (; s < e1; s++) {
      int v = csr_src[s];
      u16x8 hgv = *(const u16x8*)(hin + (size_t)v * 128 + li * 8);
      u16x8 ev = *(const u16x8*)(e_perm + (size_t)s * 128 + li * 8);
#pragma unroll
      for (int j = 0; j < 8; j++) a[j] += fmaxf(bf2f(hgv[j]) + bf2f(ev[j]), 0.f);
    }
    bf16x8 o;
#pragma unroll
    for (int j = 0; j < 8; j++) o[j] = (__bf16)(bf2f(hv[j]) + a[j]);
    *(bf16x8*)&sZ[lr * 132 + li * 8] = o;
  }
  // preload W1 fragments + bias while other waves finish aggregating
  bf16x8 w1f[8];
  float4 b1v[2];
#pragma unroll
  for (int ct = 0; ct < 2; ct++) {
    b1v[ct] = *(const float4*)&b1[w * 32 + ct * 16 + quad * 4];
#pragma unroll
    for (int kb = 0; kb < 4; kb++)
      w1f[ct * 4 + kb] = *(const bf16x8*)(w1t + (size_t)(w * 32 + ct * 16 + m) * 128 + kb * 32 + quad * 8);
  }
  __syncthreads();  // bA: sZ complete

  // ---- phase B: conv MLP (both GEMMs swapped -> D^T, LDS packs) ----
  f32x4 z4 = {0.f, 0.f, 0.f, 0.f};
  f32x4 acc[8];
#pragma unroll
  for (int i = 0; i < 8; i++) acc[i] = z4;
#pragma unroll
  for (int rt = 0; rt < 4; rt++) {
#pragma unroll
    for (int kb = 0; kb < 4; kb++) {
      bf16x8 a = *(const bf16x8*)(&sZ[(rt * 16 + m) * 132 + kb * 32 + quad * 8]);
      acc[rt * 2 + 0] = __builtin_amdgcn_mfma_f32_16x16x32_bf16(w1f[kb], a, acc[rt * 2 + 0], 0, 0, 0);
      acc[rt * 2 + 1] = __builtin_amdgcn_mfma_f32_16x16x32_bf16(w1f[4 + kb], a, acc[rt * 2 + 1], 0, 0, 0);
    }
  }
#pragma unroll
  for (int rt = 0; rt < 4; rt++) {
#pragma unroll
    for (int ct = 0; ct < 2; ct++) {
      f32x4 a4 = acc[rt * 2 + ct];
      uint2 pk;
      pk.x = pkbf(fmaxf(a4[0] + b1v[ct].x, 0.f), fmaxf(a4[1] + b1v[ct].y, 0.f));
      pk.y = pkbf(fmaxf(a4[2] + b1v[ct].z, 0.f), fmaxf(a4[3] + b1v[ct].w, 0.f));
      *(uint2*)&sMid[(rt * 16 + m) * 132 + w * 32 + ct * 16 + quad * 4] = pk;
    }
  }
  bf16x8 w2f[8];
  float4 b2v[2], gamv[2], betv[2];
#pragma unroll
  for (int ct = 0; ct < 2; ct++) {
    int c0 = w * 32 + ct * 16 + quad * 4;
    b2v[ct] = *(const float4*)&b2[c0];
    gamv[ct] = *(const float4*)&gam[c0];
    betv[ct] = *(const float4*)&bet[c0];
#pragma unroll
    for (int kb = 0; kb < 4; kb++)
      w2f[ct * 4 + kb] = *(const bf16x8*)(w2t + (size_t)(w * 32 + ct * 16 + m) * 128 + kb * 32 + quad * 8);
  }
  __syncthreads();  // b2: sMid complete (sZ reads also all done)

  f32x4 acc2[8];
#pragma unroll
  for (int i = 0; i < 8; i++) acc2[i] = z4;
#pragma unroll
  for (int rt = 0; rt < 4; rt++) {
#pragma unroll
    for (int kb = 0; kb < 4; kb++) {
      bf16x8 a = *(const bf16x8*)(&sMid[(rt * 16 + m) * 132 + kb * 32 + quad * 8]);
      acc2[rt * 2 + 0] = __builtin_amdgcn_mfma_f32_16x16x32_bf16(w2f[kb], a, acc2[rt * 2 + 0], 0, 0, 0);
      acc2[rt * 2 + 1] = __builtin_amdgcn_mfma_f32_16x16x32_bf16(w2f[4 + kb], a, acc2[rt * 2 + 1], 0, 0, 0);
    }
  }
  const float bns = 0.99999500003749983f;  // 1/sqrt(1+1e-5)
  // final pack reuses sZ (its readers finished before b2)
#pragma unroll
  for (int rt = 0; rt < 4; rt++) {
#pragma unroll
    for (int ct = 0; ct < 2; ct++) {
      f32x4 a4 = acc2[rt * 2 + ct];
      uint2 pk;
      pk.x = pkbf(fmaxf((a4[0] + b2v[ct].x) * bns * gamv[ct].x + betv[ct].x, 0.f),
                  fmaxf((a4[1] + b2v[ct].y) * bns * gamv[ct].y + betv[ct].y, 0.f));
      pk.y = pkbf(fmaxf((a4[2] + b2v[ct].z) * bns * gamv[ct].z + betv[ct].z, 0.f),
                  fmaxf((a4[3] + b2v[ct].w) * bns * gamv[ct].w + betv[ct].w, 0.f));
      *(uint2*)&sZ[(rt * 16 + m) * 132 + w * 32 + ct * 16 + quad * 4] = pk;
    }
  }
  __syncthreads();  // b3: out tile ready
#pragma unroll
  for (int i = 0; i < 4; i++) {
    int idx = t + 256 * i; int r = idx >> 4, c = idx & 15;
    int grow = row0 + r;
    if (grow < n)
      *(uint4*)(hout + (size_t)grow * 128 + c * 8) = *(const uint4*)&sZ[r * 132 + c * 8];
  }

  if (GATE) {
    // gate from sZ (final h tile), same math as standalone gate_k
    int rbase = w * 16;
    f32x4 gacc[4];
#pragma unroll
    for (int i = 0; i < 4; i++) gacc[i] = z4;
#pragma unroll
    for (int kb = 0; kb < 4; kb++) {
      bf16x8 a = *(const bf16x8*)(&sZ[(rbase + m) * 132 + kb * 32 + quad * 8]);
#pragma unroll
      for (int nt = 0; nt < 4; nt++) {
        bf16x8 b = *(const bf16x8*)(gw1t + (nt * 16 + m) * 128 + kb * 32 + quad * 8);
        gacc[nt] = __builtin_amdgcn_mfma_f32_16x16x32_bf16(a, b, gacc[nt], 0, 0, 0);
      }
    }
    float gb1v[4], gw2v[4];
#pragma unroll
    for (int nt = 0; nt < 4; nt++) { gb1v[nt] = gb1[nt * 16 + m]; gw2v[nt] = gw2[nt * 16 + m]; }
    float gb2v = gb2[0];
#pragma unroll
    for (int r = 0; r < 4; r++) {
      float p = 0.f;
#pragma unroll
      for (int nt = 0; nt < 4; nt++) p += fmaxf(gacc[nt][r] + gb1v[nt], 0.f) * gw2v[nt];
      p += __shfl_xor(p, 1, 64);
      p += __shfl_xor(p, 2, 64);
      p += __shfl_xor(p, 4, 64);
      p += __shfl_xor(p, 8, 64);
      if (m == 0) {
        int grow = row0 + rbase + quad * 4 + r;
        if (grow < n) gate_out[grow] = p + gb2v;
      }
    }
  }
}

// ---------------- pooled segment softmax + head (fused) ---------------------
__global__ __launch_bounds__(256) void pool_head_k(const float* __restrict__ gate,
                                                   const u16* __restrict__ hb,
                                                   const int* __restrict__ goffs,
                                                   const float* __restrict__ hw1,
                                                   const float* __restrict__ hb1,
                                                   const float* __restrict__ hw2,
                                                   const float* __restrict__ hb2,
                                                   float* __restrict__ out) {
  int g = blockIdx.x, t = threadIdx.x;  // 256 threads
  int s0 = goffs[g], s1 = goffs[g + 1];
  int lane = t & 63, w = t >> 6;
  __shared__ float red[4];
  __shared__ float fin[2][128];
  __shared__ float shid[128];
  float mx = -3.4e38f;
  for (int i = s0 + t; i < s1; i += 256) mx = fmaxf(mx, gate[i]);
  for (int d = 32; d; d >>= 1) mx = fmaxf(mx, __shfl_xor(mx, d, 64));
  if (lane == 0) red[w] = mx;
  __syncthreads();
  mx = fmaxf(fmaxf(red[0], red[1]), fmaxf(red[2], red[3]));
  __syncthreads();
  float sm = 0.f;
  for (int i = s0 + t; i < s1; i += 256) sm += __expf(gate[i] - mx);
  for (int d = 32; d; d >>= 1) sm += __shfl_xor(sm, d, 64);
  if (lane == 0) red[w] = sm;
  __syncthreads();
  sm = red[0] + red[1] + red[2] + red[3];
  int g2 = t >> 7, tc = t & 127;
  float acc = 0.f;
  for (int i = s0 + g2; i < s1; i += 2)
    acc += __expf(gate[i] - mx) * bf2f(hb[(size_t)i * 128 + tc]);
  fin[g2][tc] = acc;
  __syncthreads();
  if (t < 128) fin[0][t] = (s1 > s0) ? (fin[0][t] + fin[1][t]) / sm : 0.f;
  __syncthreads();
  // head: hid = relu(g @ hw1 + hb1); out = hid @ hw2 + hb2
  if (t < 128) {
    float s = 0.f;
    for (int k = 0; k < 128; k++) s += fin[0][k] * hw1[k * 128 + t];
    shid[t] = fmaxf(s + hb1[t], 0.f);
  }
  __syncthreads();
  if (t < 5) {
    float o = hb2[t];
    for (int k = 0; k < 128; k++) o += shid[k] * hw2[k * 5 + t];
    out[g * 5 + t] = o;
  }
}

// ---------------- launcher ---------------------------------------------------
extern "C" void kernel_launch(void* const* d_in, const int* in_sizes, int n_in,
                              void* d_out, int out_size, void* d_ws, size_t ws_size,
                              hipStream_t stream) {
  const int N = NNODES, E = NEDGES, G = NGRAPH;
  const float* x = (const float*)d_in[0];
  const float* edge_attr = (const float*)d_in[1];
  const float* node_w = (const float*)d_in[2];
  const float* node_b = (const float*)d_in[3];
  const float* edge_w1 = (const float*)d_in[4];
  const float* edge_b1 = (const float*)d_in[5];
  const float* edge_w2 = (const float*)d_in[6];
  const float* edge_b2 = (const float*)d_in[7];
  const float* conv_w1 = (const float*)d_in[8];
  const float* conv_b1 = (const float*)d_in[9];
  const float* conv_w2 = (const float*)d_in[10];
  const float* conv_b2 = (const float*)d_in[11];
  const float* bn_gamma = (const float*)d_in[12];
  const float* bn_beta = (const float*)d_in[13];
  const float* gate_w1 = (const float*)d_in[14];
  const float* gate_b1 = (const float*)d_in[15];
  const float* gate_w2 = (const float*)d_in[16];
  const float* gate_b2 = (const float*)d_in[17];
  const float* head_w1 = (const float*)d_in[18];
  const float* head_b1 = (const float*)d_in[19];
  const float* head_w2 = (const float*)d_in[20];
  const float* head_b2 = (const float*)d_in[21];
  const int* eidx = (const int*)d_in[22];
  const int* batch = (const int*)d_in[23];
  const int* esrc = eidx;
  const int* edst = eidx + E;

  char* wp = (char*)d_ws;
  auto alloc = [&](size_t bytes) { char* p = wp; wp += (bytes + 255) & ~(size_t)255; return p; };
  u16* e_perm = (u16*)alloc((size_t)E * 128 * 2);
  u16* hb = (u16*)alloc((size_t)(N + 16) * 128 * 2);   // +pad for tile overread
  u16* hb2 = (u16*)alloc((size_t)(N + 16) * 128 * 2);  // ping-pong partner
  float* gate = (float*)alloc((size_t)N * 4);
  int* counts = (int*)alloc((size_t)N * 4);
  int* offs = (int*)alloc((size_t)(N + 1) * 4);
  int* partial = (int*)alloc((size_t)HSPLIT * N * 4);
  int* csr_src = (int*)alloc((size_t)E * 4);
  int* inv = (int*)alloc((size_t)E * 4);
  int* bsums = (int*)alloc(256 * 4);
  int* goffs = (int*)alloc((G + 1) * 4);
  u16* node_wt = (u16*)alloc(8192 * 2);
  u16* edge_w1t = (u16*)alloc(4096 * 2);
  u16* edge_w2t = (u16*)alloc(16384 * 2);
  u16* conv_w1t = (u16*)alloc(65536 * 2);
  u16* conv_w2t = (u16*)alloc(65536 * 2);
  u16* gate_w1t = (u16*)alloc(8192 * 2);

  size_t need = (size_t)(wp - (char*)d_ws);
  if (need > ws_size) {
    write_zero_f32<<<(out_size + 255) / 256, 256, 0, stream>>>((float*)d_out, out_size);
    return;
  }

  prep_weights<<<656, 256, 0, stream>>>(node_w, edge_w1, edge_w2, conv_w1, conv_w2, gate_w1,
                                        node_wt, edge_w1t, edge_w2t, conv_w1t, conv_w2t, gate_w1t);
  hist_k<<<NCHUNK * HSPLIT, 256, 0, stream>>>(edst, partial);
  scan_a<<<197, 256, 0, stream>>>(partial, counts, bsums, batch, goffs, N);
  scan_c<<<196, 256, 0, stream>>>(counts, bsums, offs, N);
  scatter_k<<<NCHUNK * HSPLIT, 256, 0, stream>>>(esrc, edst, offs, partial, csr_src, inv);
  node_encode<<<(N + 63) / 64, 256, 0, stream>>>(x, node_wt, node_b, hb, N);
  edge_encode<<<E / 128, 256, 0, stream>>>(edge_attr, edge_w1t, edge_w2t, edge_b1, edge_b2,
                                           inv, e_perm);
  u16* hcur = hb;
  u16* hnext = hb2;
  for (int l = 0; l < 4; l++) {
    if (l < 3)
      layer_k<false><<<(N + 63) / 64, 256, 0, stream>>>(hcur, hnext, e_perm, offs, csr_src,
                                                        conv_w1t + l * 16384, conv_w2t + l * 16384,
                                                        conv_b1 + l * 128, conv_b2 + l * 128,
                                                        bn_gamma + l * 128, bn_beta + l * 128,
                                                        gate_w1t, gate_b1, gate_w2, gate_b2,
                                                        (float*)nullptr, N);
    else
      layer_k<true><<<(N + 63) / 64, 256, 0, stream>>>(hcur, hnext, e_perm, offs, csr_src,
                                                       conv_w1t + l * 16384, conv_w2t + l * 16384,
                                                       conv_b1 + l * 128, conv_b2 + l * 128,
                                                       bn_gamma + l * 128, bn_beta + l * 128,
                                                       gate_w1t, gate_b1, gate_w2, gate_b2,
                                                       gate, N);
    u16* tmp = hcur; hcur = hnext; hnext = tmp;
  }
  pool_head_k<<<G, 256, 0, stream>>>(gate, hcur, goffs, head_w1, head_b1, head_w2, head_b2,
                                     (float*)d_out);
}

// Round 12
// 553.718 us; speedup vs baseline: 1.0917x; 1.0917x over previous
//
#include <hip/hip_runtime.h>

typedef unsigned short u16;
typedef __bf16 bf16x8 __attribute__((ext_vector_type(8)));
typedef __bf16 bf16x2 __attribute__((ext_vector_type(2)));
typedef float f32x4 __attribute__((ext_vector_type(4)));
typedef unsigned short u16x8 __attribute__((ext_vector_type(8)));

#define NNODES 50000
#define NEDGES 640000
#define NGRAPH 256
#define HCHUNK 4096
#define HSPLIT 64
#define NCHUNK 13  // ceil(50000/4096)

__device__ __forceinline__ float bf2f(u16 u) {
  unsigned int v = ((unsigned int)u) << 16; float f; __builtin_memcpy(&f, &v, 4); return f;
}
__device__ __forceinline__ u16 f2bf(float f) {
  unsigned int x; __builtin_memcpy(&x, &f, 4);
  unsigned int lsb = (x >> 16) & 1u;
  x += 0x7fffu + lsb;
  return (u16)(x >> 16);
}
// packed bf16 pair via native casts (compiles to v_cvt_pk_bf16_f32, RNE)
__device__ __forceinline__ unsigned int pkbf(float a, float b) {
  bf16x2 p; p[0] = (__bf16)a; p[1] = (__bf16)b;
  unsigned int r; __builtin_memcpy(&r, &p, 4); return r;
}

// ---------------- safe fallback: zero fp32 output ---------------------------
__global__ void write_zero_f32(float* __restrict__ out, int n) {
  int i = blockIdx.x * 256 + threadIdx.x;
  if (i < n) out[i] = 0.f;
}

// ---------------- weight prep: fp32 -> bf16 transpose (B-layout Wt[n][k]) ---
__global__ void prep_weights(const float* __restrict__ node_w, const float* __restrict__ edge_w1,
                             const float* __restrict__ edge_w2, const float* __restrict__ conv_w1,
                             const float* __restrict__ conv_w2, const float* __restrict__ gate_w1,
                             u16* __restrict__ node_wt, u16* __restrict__ edge_w1t,
                             u16* __restrict__ edge_w2t, u16* __restrict__ conv_w1t,
                             u16* __restrict__ conv_w2t, u16* __restrict__ gate_w1t) {
  int o = blockIdx.x * 256 + threadIdx.x;
  if (o < 8192) { int n = o >> 6, k = o & 63; node_wt[o] = f2bf(node_w[k * 128 + n]); return; }
  o -= 8192;
  if (o < 4096) { int n = o >> 5, k = o & 31;
                  edge_w1t[o] = (k < 16) ? f2bf(edge_w1[k * 128 + n]) : (u16)0; return; }
  o -= 4096;
  if (o < 16384) { int n = o >> 7, k = o & 127; edge_w2t[o] = f2bf(edge_w2[k * 128 + n]); return; }
  o -= 16384;
  if (o < 65536) { int l = o >> 14, r = o & 16383, n = r >> 7, k = r & 127;
                   conv_w1t[o] = f2bf(conv_w1[l * 16384 + k * 128 + n]); return; }
  o -= 65536;
  if (o < 65536) { int l = o >> 14, r = o & 16383, n = r >> 7, k = r & 127;
                   conv_w2t[o] = f2bf(conv_w2[l * 16384 + k * 128 + n]); return; }
  o -= 65536;
  if (o < 8192) { int n = o >> 7, k = o & 127; gate_w1t[o] = f2bf(gate_w1[k * 64 + n]); }
}

// ---------------- CSR build v4: atomic-free, wide scans ---------------------
__global__ __launch_bounds__(256) void hist_k(const int* __restrict__ dst,
                                              int* __restrict__ partial) {
  __shared__ int hloc[HCHUNK];
  int b = blockIdx.x, t = threadIdx.x;
  int c = b >> 6, sp = b & 63;
  for (int j = t; j < HCHUNK; j += 256) hloc[j] = 0;
  __syncthreads();
  int base = c * HCHUNK;
  int e0 = sp * (NEDGES / HSPLIT), e1 = e0 + NEDGES / HSPLIT;
  for (int i = e0 + t; i < e1; i += 256) {
    int d = dst[i] - base;
    if ((unsigned)d < HCHUNK) atomicAdd(&hloc[d], 1);
  }
  __syncthreads();
  for (int j = t; j < HCHUNK; j += 256) {
    int g = base + j;
    if (g < NNODES) partial[(size_t)sp * NNODES + g] = hloc[j];
  }
}
// blocks 0..195: 1 node/thread — merge partials -> counts, in-place
// split-exclusive prefix, per-block (256-node) sums.  block 196: goffs via
// binary search (batch is sorted).
__global__ __launch_bounds__(256) void scan_a(int* __restrict__ partial,
                                              int* __restrict__ counts,
                                              int* __restrict__ bsums,
                                              const int* __restrict__ batch,
                                              int* __restrict__ goffs, int n) {
  __shared__ int sh4[4];
  int b = blockIdx.x, t = threadIdx.x;
  int lane = t & 63, w = t >> 6;
  if (b == 196) {
    int lo = 0, hi = n;  // lower_bound(batch, t)
    while (lo < hi) { int mid = (lo + hi) >> 1; if (batch[mid] < t) lo = mid + 1; else hi = mid; }
    goffs[t] = lo;
    if (t == 0) goffs[256] = n;
    return;
  }
  int g = b * 256 + t;
  int run = 0;
  if (g < n) {
    for (int sp = 0; sp < HSPLIT; sp++) {
      int v = partial[(size_t)sp * NNODES + g];
      partial[(size_t)sp * NNODES + g] = run;
      run += v;
    }
    counts[g] = run;
  }
  int s = run;
  for (int mm = 32; mm; mm >>= 1) s += __shfl_xor(s, mm, 64);
  if (lane == 0) sh4[w] = s;
  __syncthreads();
  if (t == 0) bsums[b] = sh4[0] + sh4[1] + sh4[2] + sh4[3];
}
// offsets: 196 blocks, 1 node/thread; block-parallel prefix of bsums
__global__ __launch_bounds__(256) void scan_c(const int* __restrict__ counts,
                                              const int* __restrict__ bsums,
                                              int* __restrict__ offs, int n) {
  __shared__ int sh4[4];
  __shared__ int wt_[4];
  __shared__ int base_sh;
  int b = blockIdx.x, t = threadIdx.x;
  int lane = t & 63, w = t >> 6;
  // base = sum bsums[0..b)
  int v = (t < b) ? bsums[t] : 0;
  int sv = v;
  for (int mm = 32; mm; mm >>= 1) sv += __shfl_xor(sv, mm, 64);
  if (lane == 0) sh4[w] = sv;
  __syncthreads();
  if (t == 0) base_sh = sh4[0] + sh4[1] + sh4[2] + sh4[3];
  // intra-block exclusive scan of counts
  int g = b * 256 + t;
  int x = (g < n) ? counts[g] : 0;
  int inc = x;
  for (int d = 1; d < 64; d <<= 1) { int y = __shfl_up(inc, (unsigned)d, 64); if (lane >= d) inc += y; }
  if (lane == 63) wt_[w] = inc;
  __syncthreads();
  int add = base_sh;
  for (int i = 0; i < w; i++) add += wt_[i];
  int excl = add + inc - x;
  if (g < n) offs[g] = excl;
  if (b == 0 && t == 0) offs[n] = NEDGES;
}
// deterministic scatter: rank via LDS atomics, slot = offs + split-prefix + rank.
// also emits inv[i] = slot (natural edge id -> CSR position) for edge_encode.
__global__ __launch_bounds__(256) void scatter_k(const int* __restrict__ src,
                                                 const int* __restrict__ dst,
                                                 const int* __restrict__ offs,
                                                 const int* __restrict__ partial,
                                                 int* __restrict__ csr_src,
                                                 int* __restrict__ inv) {
  __shared__ int hloc[HCHUNK];
  int b = blockIdx.x, t = threadIdx.x;
  int c = b >> 6, sp = b & 63;
  for (int j = t; j < HCHUNK; j += 256) hloc[j] = 0;
  __syncthreads();
  int base = c * HCHUNK;
  int e0 = sp * (NEDGES / HSPLIT), e1 = e0 + NEDGES / HSPLIT;
  for (int i = e0 + t; i < e1; i += 256) {
    int d = dst[i];
    int dl = d - base;
    if ((unsigned)dl < HCHUNK) {
      int r = atomicAdd(&hloc[dl], 1);
      int p = offs[d] + partial[(size_t)sp * NNODES + d] + r;
      csr_src[p] = src[i];
      inv[i] = p;
    }
  }
}

// ---------------- MFMA tile helper (A,B both from LDS) ----------------------
template <int KB, int SA, int SB>
__device__ __forceinline__ void mfma_block(const u16* aL, const u16* bL, int m, int quad,
                                           int rbase, f32x4* acc) {
#pragma unroll
  for (int kb = 0; kb < KB; ++kb) {
    bf16x8 a = *(const bf16x8*)(aL + (rbase + m) * SA + kb * 32 + quad * 8);
#pragma unroll
    for (int nt = 0; nt < 8; ++nt) {
      bf16x8 b = *(const bf16x8*)(bL + (nt * 16 + m) * SB + kb * 32 + quad * 8);
      acc[nt] = __builtin_amdgcn_mfma_f32_16x16x32_bf16(a, b, acc[nt], 0, 0, 0);
    }
  }
}

// ---------------- node encoder: hb = bf16(x @ node_w + node_b) --------------
__global__ __launch_bounds__(256) void node_encode(const float* __restrict__ x,
                                                   const u16* __restrict__ wt,
                                                   const float* __restrict__ nb,
                                                   u16* __restrict__ hb, int n) {
  __shared__ alignas(16) u16 sA[64 * 72];
  __shared__ alignas(16) u16 sW[128 * 72];
  int t = threadIdx.x;
  int row0 = blockIdx.x * 64;
#pragma unroll
  for (int i = 0; i < 4; i++) {
    int idx = t + 256 * i; int r = idx >> 4, c = idx & 15;  // 64 rows x 16 float4 (K=64)
    int grow = row0 + r; if (grow > n - 1) grow = n - 1;
    float4 v = *(const float4*)(x + (size_t)grow * 64 + c * 4);
    ushort4 o; o.x = f2bf(v.x); o.y = f2bf(v.y); o.z = f2bf(v.z); o.w = f2bf(v.w);
    *(ushort4*)&sA[r * 72 + c * 4] = o;
  }
#pragma unroll
  for (int i = 0; i < 4; i++) {
    int idx = t + 256 * i; int nr = idx >> 3, c = idx & 7;  // 128 rows x 8 uint4 (K=64)
    *(uint4*)&sW[nr * 72 + c * 8] = *(const uint4*)(wt + nr * 64 + c * 8);
  }
  __syncthreads();
  int lane = t & 63, w = t >> 6, m = lane & 15, quad = lane >> 4, rbase = w * 16;
  f32x4 acc[8];
  f32x4 z4 = {0.f, 0.f, 0.f, 0.f};
#pragma unroll
  for (int i = 0; i < 8; i++) acc[i] = z4;
  mfma_block<2, 72, 72>(sA, sW, m, quad, rbase, acc);
#pragma unroll
  for (int nt = 0; nt < 8; nt++) {
    int col = nt * 16 + m;
    float bb = nb[col];
    f32x4 a4 = acc[nt];
#pragma unroll
    for (int r = 0; r < 4; r++) {
      int grow = row0 + rbase + quad * 4 + r;
      if (grow < n) hb[(size_t)grow * 128 + col] = f2bf(a4[r] + bb);
    }
  }
}

// ---------------- edge encoder v13: natural-order reads, scattered writes ---
// (verified r11: 84.4us, FETCH 41->21.5MB)  Random side moved to the store
// path; ea reads fully sequential; csr_eid gather gone.
__global__ __launch_bounds__(256) void edge_encode(const float* __restrict__ ea,
                                                   const u16* __restrict__ w1t,
                                                   const u16* __restrict__ w2t,
                                                   const float* __restrict__ b1,
                                                   const float* __restrict__ b2,
                                                   const int* __restrict__ inv,
                                                   u16* __restrict__ e_perm) {
  __shared__ alignas(16) u16 sMid[128 * 132]; // GEMM1 out / GEMM2 in / out tile
  int t = threadIdx.x;
  int lane = t & 63, w = t >> 6, m = lane & 15, quad = lane >> 4;
  int s0 = blockIdx.x * 128;
  int ebase = w * 32;  // this wave's 32 edges (natural order)

  // sequential coalesced global -> reg A-fragments (no barrier before GEMM1)
  bf16x8 af[2];
#pragma unroll
  for (int rt2 = 0; rt2 < 2; rt2++) {
    int eid = s0 + ebase + rt2 * 16 + m;
    bf16x8 a = {};
    if (quad < 2) {
      float4 v0 = *(const float4*)(ea + (size_t)eid * 16 + quad * 8);
      float4 v1 = *(const float4*)(ea + (size_t)eid * 16 + quad * 8 + 4);
      a[0] = (__bf16)v0.x; a[1] = (__bf16)v0.y; a[2] = (__bf16)v0.z; a[3] = (__bf16)v0.w;
      a[4] = (__bf16)v1.x; a[5] = (__bf16)v1.y; a[6] = (__bf16)v1.z; a[7] = (__bf16)v1.w;
    }
    af[rt2] = a;
  }
  bf16x8 w1f[8];
#pragma unroll
  for (int nt = 0; nt < 8; nt++)
    w1f[nt] = *(const bf16x8*)(w1t + (nt * 16 + m) * 32 + quad * 8);

  // GEMM1 (swapped -> D^T), wave-local: 2 row-tiles x 8 ch-tiles
  f32x4 z4 = {0.f, 0.f, 0.f, 0.f};
  f32x4 acc1[16];
#pragma unroll
  for (int i = 0; i < 16; i++) acc1[i] = z4;
#pragma unroll
  for (int rt2 = 0; rt2 < 2; rt2++) {
#pragma unroll
    for (int nt = 0; nt < 8; nt++)
      acc1[rt2 * 8 + nt] = __builtin_amdgcn_mfma_f32_16x16x32_bf16(w1f[nt], af[rt2], acc1[rt2 * 8 + nt], 0, 0, 0);
  }
#pragma unroll
  for (int rt2 = 0; rt2 < 2; rt2++) {
#pragma unroll
    for (int nt = 0; nt < 8; nt++) {
      float4 bb = *(const float4*)&b1[nt * 16 + quad * 4];
      f32x4 a4 = acc1[rt2 * 8 + nt];
      uint2 pk;
      pk.x = pkbf(fmaxf(a4[0] + bb.x, 0.f), fmaxf(a4[1] + bb.y, 0.f));
      pk.y = pkbf(fmaxf(a4[2] + bb.z, 0.f), fmaxf(a4[3] + bb.w, 0.f));
      *(uint2*)&sMid[(ebase + rt2 * 16 + m) * 132 + nt * 16 + quad * 4] = pk;
    }
  }
  bf16x8 w2f[8];
  float4 b2v[2];
#pragma unroll
  for (int ct = 0; ct < 2; ct++) {
    b2v[ct] = *(const float4*)&b2[w * 32 + ct * 16 + quad * 4];
#pragma unroll
    for (int kb = 0; kb < 4; kb++)
      w2f[ct * 4 + kb] = *(const bf16x8*)(w2t + (size_t)(w * 32 + ct * 16 + m) * 128 + kb * 32 + quad * 8);
  }
  __syncthreads();  // b2: sMid complete

  f32x4 acc2[16];
#pragma unroll
  for (int i = 0; i < 16; i++) acc2[i] = z4;
#pragma unroll
  for (int rt = 0; rt < 8; rt++) {
#pragma unroll
    for (int kb = 0; kb < 4; kb++) {
      bf16x8 a = *(const bf16x8*)(&sMid[(rt * 16 + m) * 132 + kb * 32 + quad * 8]);
      acc2[rt * 2 + 0] = __builtin_amdgcn_mfma_f32_16x16x32_bf16(w2f[kb], a, acc2[rt * 2 + 0], 0, 0, 0);
      acc2[rt * 2 + 1] = __builtin_amdgcn_mfma_f32_16x16x32_bf16(w2f[4 + kb], a, acc2[rt * 2 + 1], 0, 0, 0);
    }
  }
  __syncthreads();  // b3: all sMid reads done -> reuse as output tile
#pragma unroll
  for (int rt = 0; rt < 8; rt++) {
#pragma unroll
    for (int ct = 0; ct < 2; ct++) {
      f32x4 a4 = acc2[rt * 2 + ct];
      uint2 pk;
      pk.x = pkbf(a4[0] + b2v[ct].x, a4[1] + b2v[ct].y);
      pk.y = pkbf(a4[2] + b2v[ct].z, a4[3] + b2v[ct].w);
      *(uint2*)&sMid[(rt * 16 + m) * 132 + w * 32 + ct * 16 + quad * 4] = pk;
    }
  }
  __syncthreads();  // b4: out tile ready
  // scattered row copy-out: row r -> CSR slot inv[s0+r]; 256B contiguous/row
#pragma unroll
  for (int i = 0; i < 8; i++) {
    int idx = t + 256 * i; int r = idx >> 4, c = idx & 15;
    int R = inv[s0 + r];
    *(uint4*)(e_perm + (size_t)R * 128 + c * 8) = *(const uint4*)&sMid[r * 132 + c * 8];
  }
}

// ---------------- fused layer v5 (r10-verified): per-quarter, 2-edge unroll -
// r11's 4-edge unroll regressed ~10us/layer (VGPR pressure -> occupancy) —
// reverted to the 566us configuration.  GATE=true (last layer): gate MLP runs
// from sZ in-place.
template <bool GATE>
__global__ __launch_bounds__(256) void layer_k(const u16* __restrict__ hin,
                                               u16* __restrict__ hout,
                                               const u16* __restrict__ e_perm,
                                               const int* __restrict__ offs,
                                               const int* __restrict__ csr_src,
                                               const u16* __restrict__ w1t, const u16* __restrict__ w2t,
                                               const float* __restrict__ b1, const float* __restrict__ b2,
                                               const float* __restrict__ gam, const float* __restrict__ bet,
                                               const u16* __restrict__ gw1t, const float* __restrict__ gb1,
                                               const float* __restrict__ gw2, const float* __restrict__ gb2,
                                               float* __restrict__ gate_out, int n) {
  __shared__ alignas(16) u16 sZ[64 * 132];
  __shared__ alignas(16) u16 sMid[64 * 132];
  int t = threadIdx.x;
  int lane = t & 63, w = t >> 6, m = lane & 15, quad = lane >> 4;
  int row0 = blockIdx.x * 64;
  int li = m;

  // batched offs: one lane-parallel load for the wave's 17 boundaries
  int oidx = row0 + w * 16 + (lane < 16 ? lane : 16);
  if (oidx > n) oidx = n;
  int offv = offs[oidx];

  // ---- phase A: quarter (w,quad) owns nodes w*16+quad*4+{0..3} ----
  for (int k = 0; k < 4; k++) {
    int lr = w * 16 + quad * 4 + k;
    int nd = row0 + lr;
    int ndc = (nd > n - 1) ? (n - 1) : nd;
    int e0 = __shfl(offv, quad * 4 + k, 64), e1 = __shfl(offv, quad * 4 + k + 1, 64);
    u16x8 hv = *(const u16x8*)(hin + (size_t)ndc * 128 + li * 8);
    float a[8];
#pragma unroll
    for (int j = 0; j < 8; j++) a[j] = 0.f;
    int s = e0;
    for (; s + 2 <= e1; s += 2) {
      int v0 = csr_src[s], v1 = csr_src[s + 1];
      u16x8 h0 = *(const u16x8*)(hin + (size_t)v0 * 128 + li * 8);
      u16x8 ee0 = *(const u16x8*)(e_perm + (size_t)s * 128 + li * 8);
      u16x8 h1 = *(const u16x8*)(hin + (size_t)v1 * 128 + li * 8);
      u16x8 ee1 = *(const u16x8*)(e_perm + (size_t)(s + 1) * 128 + li * 8);
#pragma unroll
      for (int j = 0; j < 8; j++) {
        a[j] += fmaxf(bf2f(h0[j]) + bf2f(ee0[j]), 0.f);
        a[j] += fmaxf(bf2f(h1[j]) + bf2f(ee1[j]), 0.f);
      }
    }
    if (s < e1) {
      int v = csr_src[s];
      u16x8 hgv = *(const u16x8*)(hin + (size_t)v * 128 + li * 8);
      u16x8 ev = *(const u16x8*)(e_perm + (size_t)s * 128 + li * 8);
#pragma unroll
      for (int j = 0; j < 8; j++) a[j] += fmaxf(bf2f(hgv[j]) + bf2f(ev[j]), 0.f);
    }
    bf16x8 o;
#pragma unroll
    for (int j = 0; j < 8; j++) o[j] = (__bf16)(bf2f(hv[j]) + a[j]);
    *(bf16x8*)&sZ[lr * 132 + li * 8] = o;
  }
  // preload W1 fragments + bias while other waves finish aggregating
  bf16x8 w1f[8];
  float4 b1v[2];
#pragma unroll
  for (int ct = 0; ct < 2; ct++) {
    b1v[ct] = *(const float4*)&b1[w * 32 + ct * 16 + quad * 4];
#pragma unroll
    for (int kb = 0; kb < 4; kb++)
      w1f[ct * 4 + kb] = *(const bf16x8*)(w1t + (size_t)(w * 32 + ct * 16 + m) * 128 + kb * 32 + quad * 8);
  }
  __syncthreads();  // bA: sZ complete

  // ---- phase B: conv MLP (both GEMMs swapped -> D^T, LDS packs) ----
  f32x4 z4 = {0.f, 0.f, 0.f, 0.f};
  f32x4 acc[8];
#pragma unroll
  for (int i = 0; i < 8; i++) acc[i] = z4;
#pragma unroll
  for (int rt = 0; rt < 4; rt++) {
#pragma unroll
    for (int kb = 0; kb < 4; kb++) {
      bf16x8 a = *(const bf16x8*)(&sZ[(rt * 16 + m) * 132 + kb * 32 + quad * 8]);
      acc[rt * 2 + 0] = __builtin_amdgcn_mfma_f32_16x16x32_bf16(w1f[kb], a, acc[rt * 2 + 0], 0, 0, 0);
      acc[rt * 2 + 1] = __builtin_amdgcn_mfma_f32_16x16x32_bf16(w1f[4 + kb], a, acc[rt * 2 + 1], 0, 0, 0);
    }
  }
#pragma unroll
  for (int rt = 0; rt < 4; rt++) {
#pragma unroll
    for (int ct = 0; ct < 2; ct++) {
      f32x4 a4 = acc[rt * 2 + ct];
      uint2 pk;
      pk.x = pkbf(fmaxf(a4[0] + b1v[ct].x, 0.f), fmaxf(a4[1] + b1v[ct].y, 0.f));
      pk.y = pkbf(fmaxf(a4[2] + b1v[ct].z, 0.f), fmaxf(a4[3] + b1v[ct].w, 0.f));
      *(uint2*)&sMid[(rt * 16 + m) * 132 + w * 32 + ct * 16 + quad * 4] = pk;
    }
  }
  bf16x8 w2f[8];
  float4 b2v[2], gamv[2], betv[2];
#pragma unroll
  for (int ct = 0; ct < 2; ct++) {
    int c0 = w * 32 + ct * 16 + quad * 4;
    b2v[ct] = *(const float4*)&b2[c0];
    gamv[ct] = *(const float4*)&gam[c0];
    betv[ct] = *(const float4*)&bet[c0];
#pragma unroll
    for (int kb = 0; kb < 4; kb++)
      w2f[ct * 4 + kb] = *(const bf16x8*)(w2t + (size_t)(w * 32 + ct * 16 + m) * 128 + kb * 32 + quad * 8);
  }
  __syncthreads();  // b2: sMid complete (sZ reads also all done)

  f32x4 acc2[8];
#pragma unroll
  for (int i = 0; i < 8; i++) acc2[i] = z4;
#pragma unroll
  for (int rt = 0; rt < 4; rt++) {
#pragma unroll
    for (int kb = 0; kb < 4; kb++) {
      bf16x8 a = *(const bf16x8*)(&sMid[(rt * 16 + m) * 132 + kb * 32 + quad * 8]);
      acc2[rt * 2 + 0] = __builtin_amdgcn_mfma_f32_16x16x32_bf16(w2f[kb], a, acc2[rt * 2 + 0], 0, 0, 0);
      acc2[rt * 2 + 1] = __builtin_amdgcn_mfma_f32_16x16x32_bf16(w2f[4 + kb], a, acc2[rt * 2 + 1], 0, 0, 0);
    }
  }
  const float bns = 0.99999500003749983f;  // 1/sqrt(1+1e-5)
  // final pack reuses sZ (its readers finished before b2)
#pragma unroll
  for (int rt = 0; rt < 4; rt++) {
#pragma unroll
    for (int ct = 0; ct < 2; ct++) {
      f32x4 a4 = acc2[rt * 2 + ct];
      uint2 pk;
      pk.x = pkbf(fmaxf((a4[0] + b2v[ct].x) * bns * gamv[ct].x + betv[ct].x, 0.f),
                  fmaxf((a4[1] + b2v[ct].y) * bns * gamv[ct].y + betv[ct].y, 0.f));
      pk.y = pkbf(fmaxf((a4[2] + b2v[ct].z) * bns * gamv[ct].z + betv[ct].z, 0.f),
                  fmaxf((a4[3] + b2v[ct].w) * bns * gamv[ct].w + betv[ct].w, 0.f));
      *(uint2*)&sZ[(rt * 16 + m) * 132 + w * 32 + ct * 16 + quad * 4] = pk;
    }
  }
  __syncthreads();  // b3: out tile ready
#pragma unroll
  for (int i = 0; i < 4; i++) {
    int idx = t + 256 * i; int r = idx >> 4, c = idx & 15;
    int grow = row0 + r;
    if (grow < n)
      *(uint4*)(hout + (size_t)grow * 128 + c * 8) = *(const uint4*)&sZ[r * 132 + c * 8];
  }

  if (GATE) {
    // gate from sZ (final h tile), same math as standalone gate_k
    int rbase = w * 16;
    f32x4 gacc[4];
#pragma unroll
    for (int i = 0; i < 4; i++) gacc[i] = z4;
#pragma unroll
    for (int kb = 0; kb < 4; kb++) {
      bf16x8 a = *(const bf16x8*)(&sZ[(rbase + m) * 132 + kb * 32 + quad * 8]);
#pragma unroll
      for (int nt = 0; nt < 4; nt++) {
        bf16x8 b = *(const bf16x8*)(gw1t + (nt * 16 + m) * 128 + kb * 32 + quad * 8);
        gacc[nt] = __builtin_amdgcn_mfma_f32_16x16x32_bf16(a, b, gacc[nt], 0, 0, 0);
      }
    }
    float gb1v[4], gw2v[4];
#pragma unroll
    for (int nt = 0; nt < 4; nt++) { gb1v[nt] = gb1[nt * 16 + m]; gw2v[nt] = gw2[nt * 16 + m]; }
    float gb2v = gb2[0];
#pragma unroll
    for (int r = 0; r < 4; r++) {
      float p = 0.f;
#pragma unroll
      for (int nt = 0; nt < 4; nt++) p += fmaxf(gacc[nt][r] + gb1v[nt], 0.f) * gw2v[nt];
      p += __shfl_xor(p, 1, 64);
      p += __shfl_xor(p, 2, 64);
      p += __shfl_xor(p, 4, 64);
      p += __shfl_xor(p, 8, 64);
      if (m == 0) {
        int grow = row0 + rbase + quad * 4 + r;
        if (grow < n) gate_out[grow] = p + gb2v;
      }
    }
  }
}

// ---------------- pooled segment softmax + head (fused) ---------------------
__global__ __launch_bounds__(256) void pool_head_k(const float* __restrict__ gate,
                                                   const u16* __restrict__ hb,
                                                   const int* __restrict__ goffs,
                                                   const float* __restrict__ hw1,
                                                   const float* __restrict__ hb1,
                                                   const float* __restrict__ hw2,
                                                   const float* __restrict__ hb2,
                                                   float* __restrict__ out) {
  int g = blockIdx.x, t = threadIdx.x;  // 256 threads
  int s0 = goffs[g], s1 = goffs[g + 1];
  int lane = t & 63, w = t >> 6;
  __shared__ float red[4];
  __shared__ float fin[2][128];
  __shared__ float shid[128];
  float mx = -3.4e38f;
  for (int i = s0 + t; i < s1; i += 256) mx = fmaxf(mx, gate[i]);
  for (int d = 32; d; d >>= 1) mx = fmaxf(mx, __shfl_xor(mx, d, 64));
  if (lane == 0) red[w] = mx;
  __syncthreads();
  mx = fmaxf(fmaxf(red[0], red[1]), fmaxf(red[2], red[3]));
  __syncthreads();
  float sm = 0.f;
  for (int i = s0 + t; i < s1; i += 256) sm += __expf(gate[i] - mx);
  for (int d = 32; d; d >>= 1) sm += __shfl_xor(sm, d, 64);
  if (lane == 0) red[w] = sm;
  __syncthreads();
  sm = red[0] + red[1] + red[2] + red[3];
  int g2 = t >> 7, tc = t & 127;
  float acc = 0.f;
  for (int i = s0 + g2; i < s1; i += 2)
    acc += __expf(gate[i] - mx) * bf2f(hb[(size_t)i * 128 + tc]);
  fin[g2][tc] = acc;
  __syncthreads();
  if (t < 128) fin[0][t] = (s1 > s0) ? (fin[0][t] + fin[1][t]) / sm : 0.f;
  __syncthreads();
  // head: hid = relu(g @ hw1 + hb1); out = hid @ hw2 + hb2
  if (t < 128) {
    float s = 0.f;
    for (int k = 0; k < 128; k++) s += fin[0][k] * hw1[k * 128 + t];
    shid[t] = fmaxf(s + hb1[t], 0.f);
  }
  __syncthreads();
  if (t < 5) {
    float o = hb2[t];
    for (int k = 0; k < 128; k++) o += shid[k] * hw2[k * 5 + t];
    out[g * 5 + t] = o;
  }
}

// ---------------- launcher ---------------------------------------------------
extern "C" void kernel_launch(void* const* d_in, const int* in_sizes, int n_in,
                              void* d_out, int out_size, void* d_ws, size_t ws_size,
                              hipStream_t stream) {
  const int N = NNODES, E = NEDGES, G = NGRAPH;
  const float* x = (const float*)d_in[0];
  const float* edge_attr = (const float*)d_in[1];
  const float* node_w = (const float*)d_in[2];
  const float* node_b = (const float*)d_in[3];
  const float* edge_w1 = (const float*)d_in[4];
  const float* edge_b1 = (const float*)d_in[5];
  const float* edge_w2 = (const float*)d_in[6];
  const float* edge_b2 = (const float*)d_in[7];
  const float* conv_w1 = (const float*)d_in[8];
  const float* conv_b1 = (const float*)d_in[9];
  const float* conv_w2 = (const float*)d_in[10];
  const float* conv_b2 = (const float*)d_in[11];
  const float* bn_gamma = (const float*)d_in[12];
  const float* bn_beta = (const float*)d_in[13];
  const float* gate_w1 = (const float*)d_in[14];
  const float* gate_b1 = (const float*)d_in[15];
  const float* gate_w2 = (const float*)d_in[16];
  const float* gate_b2 = (const float*)d_in[17];
  const float* head_w1 = (const float*)d_in[18];
  const float* head_b1 = (const float*)d_in[19];
  const float* head_w2 = (const float*)d_in[20];
  const float* head_b2 = (const float*)d_in[21];
  const int* eidx = (const int*)d_in[22];
  const int* batch = (const int*)d_in[23];
  const int* esrc = eidx;
  const int* edst = eidx + E;

  char* wp = (char*)d_ws;
  auto alloc = [&](size_t bytes) { char* p = wp; wp += (bytes + 255) & ~(size_t)255; return p; };
  u16* e_perm = (u16*)alloc((size_t)E * 128 * 2);
  u16* hb = (u16*)alloc((size_t)(N + 16) * 128 * 2);   // +pad for tile overread
  u16* hb2 = (u16*)alloc((size_t)(N + 16) * 128 * 2);  // ping-pong partner
  float* gate = (float*)alloc((size_t)N * 4);
  int* counts = (int*)alloc((size_t)N * 4);
  int* offs = (int*)alloc((size_t)(N + 1) * 4);
  int* partial = (int*)alloc((size_t)HSPLIT * N * 4);
  int* csr_src = (int*)alloc((size_t)E * 4);
  int* inv = (int*)alloc((size_t)E * 4);
  int* bsums = (int*)alloc(256 * 4);
  int* goffs = (int*)alloc((G + 1) * 4);
  u16* node_wt = (u16*)alloc(8192 * 2);
  u16* edge_w1t = (u16*)alloc(4096 * 2);
  u16* edge_w2t = (u16*)alloc(16384 * 2);
  u16* conv_w1t = (u16*)alloc(65536 * 2);
  u16* conv_w2t = (u16*)alloc(65536 * 2);
  u16* gate_w1t = (u16*)alloc(8192 * 2);

  size_t need = (size_t)(wp - (char*)d_ws);
  if (need > ws_size) {
    write_zero_f32<<<(out_size + 255) / 256, 256, 0, stream>>>((float*)d_out, out_size);
    return;
  }

  prep_weights<<<656, 256, 0, stream>>>(node_w, edge_w1, edge_w2, conv_w1, conv_w2, gate_w1,
                                        node_wt, edge_w1t, edge_w2t, conv_w1t, conv_w2t, gate_w1t);
  hist_k<<<NCHUNK * HSPLIT, 256, 0, stream>>>(edst, partial);
  scan_a<<<197, 256, 0, stream>>>(partial, counts, bsums, batch, goffs, N);
  scan_c<<<196, 256, 0, stream>>>(counts, bsums, offs, N);
  scatter_k<<<NCHUNK * HSPLIT, 256, 0, stream>>>(esrc, edst, offs, partial, csr_src, inv);
  node_encode<<<(N + 63) / 64, 256, 0, stream>>>(x, node_wt, node_b, hb, N);
  edge_encode<<<E / 128, 256, 0, stream>>>(edge_attr, edge_w1t, edge_w2t, edge_b1, edge_b2,
                                           inv, e_perm);
  u16* hcur = hb;
  u16* hnext = hb2;
  for (int l = 0; l < 4; l++) {
    if (l < 3)
      layer_k<false><<<(N + 63) / 64, 256, 0, stream>>>(hcur, hnext, e_perm, offs, csr_src,
                                                        conv_w1t + l * 16384, conv_w2t + l * 16384,
                                                        conv_b1 + l * 128, conv_b2 + l * 128,
                                                        bn_gamma + l * 128, bn_beta + l * 128,
                                                        gate_w1t, gate_b1, gate_w2, gate_b2,
                                                        (float*)nullptr, N);
    else
      layer_k<true><<<(N + 63) / 64, 256, 0, stream>>>(hcur, hnext, e_perm, offs, csr_src,
                                                       conv_w1t + l * 16384, conv_w2t + l * 16384,
                                                       conv_b1 + l * 128, conv_b2 + l * 128,
                                                       bn_gamma + l * 128, bn_beta + l * 128,
                                                       gate_w1t, gate_b1, gate_w2, gate_b2,
                                                       gate, N);
    u16* tmp = hcur; hcur = hnext; hnext = tmp;
  }
  pool_head_k<<<G, 256, 0, stream>>>(gate, hcur, goffs, head_w1, head_b1, head_w2, head_b2,
                                     (float*)d_out);
}